// Round 12
// baseline (42.838 us; speedup 1.0000x reference)
//
#include <hip/hip_runtime.h>

#define B_   16
#define T_   10
#define D_   256
#define MI_  32
#define MO_  16
#define RES_ 200
#define TWO_PI 6.28318530717958647692f

#define HH    128                 // h per block (half of D_)
#define VPAD  68                  // padded v row stride (floats)
#define CSN   (MO_ * HH)          // 2048 pairs

using f32x4 = __attribute__((ext_vector_type(4))) float;
using v2f   = __attribute__((ext_vector_type(2))) float;

// Fused kernel. grid 320 = bt(160) x hh(2); block 512 = 8 waves.
// P0: stage 32KB v-half.  P1: contraction -> C,S pairs in LDS.
// P2: 16 slot-streams (8 waves x 2 sub), lane owns 4 h, rotation trig,
//     mirror-pair rows, 512B-contiguous NT stores.
__global__ __launch_bounds__(512) void spectral_fused1(
    const float* __restrict__ v,
    const float* __restrict__ w_real,
    const float* __restrict__ w_imag,
    float* __restrict__ out)
{
    const int blk = blockIdx.x;          // 0..319
    const int bt  = blk >> 1;
    const int hh  = blk & 1;
    const int t   = bt % T_;

    __shared__ float s_v[HH * VPAD];     // 34 KB
    __shared__ float s_cs[2 * CSN];      // 16 KB: [o][h_l] -> (C,S) pairs

    // ---------------- Phase 0: stage v half (32 KB, coalesced) -------------
    {
        const float4* gv = reinterpret_cast<const float4*>(
            v + ((size_t)bt * D_ + hh * HH) * (2 * MI_));
        #pragma unroll
        for (int j = 0; j < 4; ++j) {
            const int f = threadIdx.x + 512 * j;   // float4 idx 0..2047
            const int h = f >> 4;                  // 16 float4 per row
            const int m = (f & 15) * 4;
            *reinterpret_cast<float4*>(&s_v[h * VPAD + m]) = gv[f];
        }
    }
    __syncthreads();

    // ---------------- Phase 1: contraction (4 o per thread) ----------------
    {
        const int og  = threadIdx.x & 3;
        const int h_l = threadIdx.x >> 2;    // 0..127

        float rr[MI_], ii[MI_];
        #pragma unroll
        for (int j = 0; j < 8; ++j) {
            float4 q = *reinterpret_cast<const float4*>(&s_v[h_l * VPAD + 4 * j]);
            rr[4*j+0]=q.x; rr[4*j+1]=q.y; rr[4*j+2]=q.z; rr[4*j+3]=q.w;
        }
        #pragma unroll
        for (int j = 0; j < 8; ++j) {
            float4 q = *reinterpret_cast<const float4*>(&s_v[h_l * VPAD + 32 + 4 * j]);
            ii[4*j+0]=q.x; ii[4*j+1]=q.y; ii[4*j+2]=q.z; ii[4*j+3]=q.w;
        }

        const int o0 = og * 4;
        const float* wrt = w_real + ((size_t)t * MO_ + o0) * MI_;
        const float* wit = w_imag + ((size_t)t * MO_ + o0) * MI_;

        #pragma unroll
        for (int ol = 0; ol < 4; ++ol) {
            const float4* wa = reinterpret_cast<const float4*>(wrt + ol * MI_);
            const float4* wb = reinterpret_cast<const float4*>(wit + ol * MI_);
            float c = 0.f, s = 0.f;
            #pragma unroll
            for (int mq = 0; mq < 8; ++mq) {
                float4 a4 = wa[mq];
                float4 b4 = wb[mq];
                c = fmaf(rr[4*mq+0], a4.x, c); c = fmaf(-ii[4*mq+0], b4.x, c);
                s = fmaf(rr[4*mq+0], b4.x, s); s = fmaf( ii[4*mq+0], a4.x, s);
                c = fmaf(rr[4*mq+1], a4.y, c); c = fmaf(-ii[4*mq+1], b4.y, c);
                s = fmaf(rr[4*mq+1], b4.y, s); s = fmaf( ii[4*mq+1], a4.y, s);
                c = fmaf(rr[4*mq+2], a4.z, c); c = fmaf(-ii[4*mq+2], b4.z, c);
                s = fmaf(rr[4*mq+2], b4.z, s); s = fmaf( ii[4*mq+2], a4.z, s);
                c = fmaf(rr[4*mq+3], a4.w, c); c = fmaf(-ii[4*mq+3], b4.w, c);
                s = fmaf(rr[4*mq+3], b4.w, s); s = fmaf( ii[4*mq+3], a4.w, s);
            }
            const int o = o0 + ol;
            v2f p; p.x = c; p.y = s;
            *reinterpret_cast<v2f*>(&s_cs[2 * (o * HH + h_l)]) = p;
        }
    }
    __syncthreads();

    // ---------------- Phase 2: mirror IFT, 16 slot-streams -----------------
    {
        const int wave   = threadIdx.x >> 6;      // 0..7
        const int lane   = threadIdx.x & 63;
        const int sub    = lane >> 5;             // 0/1
        const int li     = lane & 31;
        const int stream = wave * 2 + sub;        // 0..15
        const int h0     = li * 4;                // local h base

        v2f CS0[MO_], CS1[MO_], CS2[MO_], CS3[MO_];
        #pragma unroll
        for (int o = 0; o < MO_; ++o) {
            float4 q0 = *reinterpret_cast<const float4*>(&s_cs[2 * (o * HH + h0)]);
            float4 q1 = *reinterpret_cast<const float4*>(&s_cs[2 * (o * HH + h0) + 4]);
            CS0[o].x = q0.x; CS0[o].y = q0.y;
            CS1[o].x = q0.z; CS1[o].y = q0.w;
            CS2[o].x = q1.x; CS2[o].y = q1.y;
            CS3[o].x = q1.z; CS3[o].y = q1.w;
        }

        float* ob = out + (size_t)bt * RES_ * D_ + hh * HH + h0;

        #pragma unroll
        for (int k = 0; k < 7; ++k) {
            const int s = stream + 16 * k;        // slot (uniform per 32 lanes)
            if (s <= 100) {
                const float phi = (float)s * (TWO_PI / (float)RES_);
                float s1, c1;
                __sincosf(phi, &s1, &c1);

                v2f ab0 = {0.f, 0.f}, ab1 = {0.f, 0.f};
                v2f ab2 = {0.f, 0.f}, ab3 = {0.f, 0.f};
                v2f cs;  cs.x = 1.f; cs.y = 0.f;  // (cos(o*phi), sin(o*phi))
                #pragma unroll
                for (int o = 0; o < MO_; ++o) {
                    ab0 = __builtin_elementwise_fma(CS0[o], cs, ab0);
                    ab1 = __builtin_elementwise_fma(CS1[o], cs, ab1);
                    ab2 = __builtin_elementwise_fma(CS2[o], cs, ab2);
                    ab3 = __builtin_elementwise_fma(CS3[o], cs, ab3);
                    const float nc = fmaf(cs.x, c1, -(cs.y * s1));
                    const float ns = fmaf(cs.y, c1,  (cs.x * s1));
                    cs.x = nc; cs.y = ns;
                }

                const int mr = (s == 0) ? 0 : (RES_ - s);
                f32x4 lo, hi;
                lo.x = ab0.x - ab0.y; hi.x = ab0.x + ab0.y;
                lo.y = ab1.x - ab1.y; hi.y = ab1.x + ab1.y;
                lo.z = ab2.x - ab2.y; hi.z = ab2.x + ab2.y;
                lo.w = ab3.x - ab3.y; hi.w = ab3.x + ab3.y;
                // 32 lanes x 16B = 512B contiguous run per sub-wave
                __builtin_nontemporal_store(
                    lo, reinterpret_cast<f32x4*>(&ob[(size_t)s  * D_]));
                __builtin_nontemporal_store(
                    hi, reinterpret_cast<f32x4*>(&ob[(size_t)mr * D_]));
            }
        }
    }
}

extern "C" void kernel_launch(void* const* d_in, const int* in_sizes, int n_in,
                              void* d_out, int out_size, void* d_ws, size_t ws_size,
                              hipStream_t stream) {
    const float* v  = (const float*)d_in[0];
    const float* wr = (const float*)d_in[1];
    const float* wi = (const float*)d_in[2];
    float* out = (float*)d_out;
    spectral_fused1<<<B_ * T_ * 2, 512, 0, stream>>>(v, wr, wi, out);
}

// Round 13
// 28.902 us; speedup vs baseline: 1.4822x; 1.4822x over previous
//
#include <hip/hip_runtime.h>

#define B_   16
#define T_   10
#define D_   256
#define MI_  32
#define MO_  16
#define RES_ 200
#define TWO_PI 6.28318530717958647692f

#define HSLICE 32
#define NHS    (D_ / HSLICE)              // 8
#define VPAD   68
#define BT_STRIDE (2 * MO_ * D_)          // 8192 floats: [o][h] -> (C,S) pairs

using f32x4 = __attribute__((ext_vector_type(4))) float;
using v2f   = __attribute__((ext_vector_type(2))) float;

// ---------- Kernel A: contraction -> ws[bt][o][h] = (C,S) interleaved ------
// grid 1280; XCD-aligned: blk = (bt&7) + 8*((bt>>3)*8 + hs)  ->  blk%8 = bt%8
// ROUND-11 EXACT. Launched TWICE this round (idempotent) for the A/B split:
// dur = 2A + B; with round-11 dur (A + B = 21.6us): A = dur - 21.6.
__global__ __launch_bounds__(256) void spectral_cs(
    const float* __restrict__ v,
    const float* __restrict__ w_real,
    const float* __restrict__ w_imag,
    float* __restrict__ ws)
{
    const int a    = blockIdx.x;
    const int r    = a & 7;
    const int rest = a >> 3;           // 0..159
    const int hs   = rest & 7;
    const int q    = rest >> 3;        // 0..19
    const int bt   = 8 * q + r;
    const int t    = bt % T_;

    __shared__ float s_v[HSLICE * VPAD];     // 8.5 KB

    {   // cooperative v-slice stage (v read exactly once per element)
        const float4* gv = reinterpret_cast<const float4*>(
            v + ((size_t)bt * D_ + hs * HSLICE) * (2 * MI_));
        #pragma unroll
        for (int j = 0; j < 2; ++j) {
            const int f = threadIdx.x + 256 * j;
            const int h = f >> 4;
            const int m = (f & 15) * 4;
            *reinterpret_cast<float4*>(&s_v[h * VPAD + m]) = gv[f];
        }
    }
    __syncthreads();

    const int og  = threadIdx.x >> 5;
    const int h_l = threadIdx.x & 31;
    const int o0  = og * 2;
    const int h_g = hs * HSLICE + h_l;

    float rr[MI_], ii[MI_];
    #pragma unroll
    for (int j = 0; j < 8; ++j) {
        float4 q4 = *reinterpret_cast<const float4*>(&s_v[h_l * VPAD + 4 * j]);
        rr[4*j+0]=q4.x; rr[4*j+1]=q4.y; rr[4*j+2]=q4.z; rr[4*j+3]=q4.w;
    }
    #pragma unroll
    for (int j = 0; j < 8; ++j) {
        float4 q4 = *reinterpret_cast<const float4*>(&s_v[h_l * VPAD + 32 + 4 * j]);
        ii[4*j+0]=q4.x; ii[4*j+1]=q4.y; ii[4*j+2]=q4.z; ii[4*j+3]=q4.w;
    }

    const float* wrt = w_real + ((size_t)t * MO_ + o0) * MI_;
    const float* wit = w_imag + ((size_t)t * MO_ + o0) * MI_;

    float* wsb = ws + (size_t)bt * BT_STRIDE;
    #pragma unroll
    for (int ol = 0; ol < 2; ++ol) {
        const float4* wa = reinterpret_cast<const float4*>(wrt + ol * MI_);
        const float4* wb = reinterpret_cast<const float4*>(wit + ol * MI_);
        float c = 0.f, s = 0.f;
        #pragma unroll
        for (int mq = 0; mq < 8; ++mq) {
            float4 a4 = wa[mq];
            float4 b4 = wb[mq];
            c = fmaf(rr[4*mq+0], a4.x, c); c = fmaf(-ii[4*mq+0], b4.x, c);
            s = fmaf(rr[4*mq+0], b4.x, s); s = fmaf( ii[4*mq+0], a4.x, s);
            c = fmaf(rr[4*mq+1], a4.y, c); c = fmaf(-ii[4*mq+1], b4.y, c);
            s = fmaf(rr[4*mq+1], b4.y, s); s = fmaf( ii[4*mq+1], a4.y, s);
            c = fmaf(rr[4*mq+2], a4.z, c); c = fmaf(-ii[4*mq+2], b4.z, c);
            s = fmaf(rr[4*mq+2], b4.z, s); s = fmaf( ii[4*mq+2], a4.z, s);
            c = fmaf(rr[4*mq+3], a4.w, c); c = fmaf(-ii[4*mq+3], b4.w, c);
            s = fmaf(rr[4*mq+3], b4.w, s); s = fmaf( ii[4*mq+3], a4.w, s);
        }
        const int o = o0 + ol;
        v2f p; p.x = c; p.y = s;
        // interleaved pair store: 32 lanes x 8B = 256B contiguous run
        *reinterpret_cast<v2f*>(&wsb[2 * (o * D_ + h_g)]) = p;
    }
}

// ---------- Kernel B: row-wave IFT, LDS-staged CS, pk_fma, 1KB stores ------
// grid 640; XCD-aligned: blk = (bt&7) + 8*((bt>>3)*4 + qb)  ->  blk%8 = bt%8
// block 256 = 4 waves; wave = full output row; lane owns h = 4*lane..4*lane+3.
// ROUND-11 EXACT.
__global__ __launch_bounds__(256) void spectral_ift(
    const float* __restrict__ ws,
    float* __restrict__ out)
{
    const int b    = blockIdx.x;
    const int r    = b & 7;
    const int rest = b >> 3;           // 0..79
    const int qb   = rest & 3;
    const int q    = rest >> 2;        // 0..19
    const int bt   = 8 * q + r;
    const int wave = threadIdx.x >> 6;
    const int lane = threadIdx.x & 63;
    const int g    = qb * 4 + wave;    // 0..15
    const int h0   = lane * 4;

    __shared__ float s_cs[BT_STRIDE];  // 32 KB: full bt C,S pairs [o][h]

    {   // cooperative stage: 32 KB, coalesced, read ONCE per block (L2-local)
        const float4* g4 = reinterpret_cast<const float4*>(
            ws + (size_t)bt * BT_STRIDE);
        float4* s4 = reinterpret_cast<float4*>(s_cs);
        #pragma unroll
        for (int i = 0; i < 8; ++i)
            s4[threadIdx.x + 256 * i] = g4[threadIdx.x + 256 * i];
    }
    __syncthreads();

    // per-lane C,S registers from LDS (b128, full-BW pattern)
    v2f CS0[MO_], CS1[MO_], CS2[MO_], CS3[MO_];
    #pragma unroll
    for (int o = 0; o < MO_; ++o) {
        float4 q0 = *reinterpret_cast<const float4*>(&s_cs[2 * (o * D_ + h0)]);
        float4 q1 = *reinterpret_cast<const float4*>(&s_cs[2 * (o * D_ + h0) + 4]);
        CS0[o].x = q0.x; CS0[o].y = q0.y;
        CS1[o].x = q0.z; CS1[o].y = q0.w;
        CS2[o].x = q1.x; CS2[o].y = q1.y;
        CS3[o].x = q1.z; CS3[o].y = q1.w;
    }

    float* ob = out + (size_t)bt * RES_ * D_;

    #pragma unroll
    for (int k = 0; k < 7; ++k) {
        const int s = g + 16 * k;        // wave-uniform slot
        if (s <= 100) {
            const float phi = (float)s * (TWO_PI / (float)RES_);
            float s1, c1;
            __sincosf(phi, &s1, &c1);

            v2f ab0 = {0.f, 0.f}, ab1 = {0.f, 0.f};
            v2f ab2 = {0.f, 0.f}, ab3 = {0.f, 0.f};
            v2f cs;  cs.x = 1.f; cs.y = 0.f;      // (cos(o*phi), sin(o*phi))
            #pragma unroll
            for (int o = 0; o < MO_; ++o) {
                ab0 = __builtin_elementwise_fma(CS0[o], cs, ab0);
                ab1 = __builtin_elementwise_fma(CS1[o], cs, ab1);
                ab2 = __builtin_elementwise_fma(CS2[o], cs, ab2);
                ab3 = __builtin_elementwise_fma(CS3[o], cs, ab3);
                const float nc = fmaf(cs.x, c1, -(cs.y * s1));
                const float ns = fmaf(cs.y, c1,  (cs.x * s1));
                cs.x = nc; cs.y = ns;
            }

            const int mr = (s == 0) ? 0 : (RES_ - s);
            f32x4 lo, hi;
            lo.x = ab0.x - ab0.y; hi.x = ab0.x + ab0.y;
            lo.y = ab1.x - ab1.y; hi.y = ab1.x + ab1.y;
            lo.z = ab2.x - ab2.y; hi.z = ab2.x + ab2.y;
            lo.w = ab3.x - ab3.y; hi.w = ab3.x + ab3.y;
            // full-row wave store: 64 lanes x 16B = 1KB contiguous
            __builtin_nontemporal_store(
                lo, reinterpret_cast<f32x4*>(&ob[(size_t)s  * D_ + h0]));
            __builtin_nontemporal_store(
                hi, reinterpret_cast<f32x4*>(&ob[(size_t)mr * D_ + h0]));
        }
    }
}

extern "C" void kernel_launch(void* const* d_in, const int* in_sizes, int n_in,
                              void* d_out, int out_size, void* d_ws, size_t ws_size,
                              hipStream_t stream) {
    const float* v  = (const float*)d_in[0];
    const float* wr = (const float*)d_in[1];
    const float* wi = (const float*)d_in[2];
    float* out = (float*)d_out;
    float* ws  = (float*)d_ws;

    // DIAGNOSTIC ROUND: A launched twice (idempotent rewrite of identical ws
    // values). dur_us = 2A + B; round 11 gave A + B = 21.6us.
    //   => A = dur_us - 21.6 ; B = 43.2 - dur_us.
    spectral_cs <<<B_ * T_ * NHS, 256, 0, stream>>>(v, wr, wi, ws);
    spectral_cs <<<B_ * T_ * NHS, 256, 0, stream>>>(v, wr, wi, ws);
    spectral_ift<<<B_ * T_ * 4,   256, 0, stream>>>(ws, out);
}

// Round 14
// 22.243 us; speedup vs baseline: 1.9259x; 1.2994x over previous
//
#include <hip/hip_runtime.h>

#define B_   16
#define T_   10
#define D_   256
#define MI_  32
#define MO_  16
#define RES_ 200
#define TWO_PI 6.28318530717958647692f

#define HSLICE 32
#define NHS    (D_ / HSLICE)              // 8
#define VPAD   68
#define BT_STRIDE (2 * MO_ * D_)          // 8192 floats: [o][h] -> (C,S) pairs

using f32x4 = __attribute__((ext_vector_type(4))) float;
using v2f   = __attribute__((ext_vector_type(2))) float;

// ---------- Kernel A: contraction -> ws[bt][o][h] = (C,S) interleaved ------
// grid 1280; XCD-aligned. ROUND-11 EXACT (measured ~7.3us incl. launch).
__global__ __launch_bounds__(256) void spectral_cs(
    const float* __restrict__ v,
    const float* __restrict__ w_real,
    const float* __restrict__ w_imag,
    float* __restrict__ ws)
{
    const int a    = blockIdx.x;
    const int r    = a & 7;
    const int rest = a >> 3;           // 0..159
    const int hs   = rest & 7;
    const int q    = rest >> 3;        // 0..19
    const int bt   = 8 * q + r;
    const int t    = bt % T_;

    __shared__ float s_v[HSLICE * VPAD];     // 8.5 KB

    {   // cooperative v-slice stage (v read exactly once per element)
        const float4* gv = reinterpret_cast<const float4*>(
            v + ((size_t)bt * D_ + hs * HSLICE) * (2 * MI_));
        #pragma unroll
        for (int j = 0; j < 2; ++j) {
            const int f = threadIdx.x + 256 * j;
            const int h = f >> 4;
            const int m = (f & 15) * 4;
            *reinterpret_cast<float4*>(&s_v[h * VPAD + m]) = gv[f];
        }
    }
    __syncthreads();

    const int og  = threadIdx.x >> 5;
    const int h_l = threadIdx.x & 31;
    const int o0  = og * 2;
    const int h_g = hs * HSLICE + h_l;

    float rr[MI_], ii[MI_];
    #pragma unroll
    for (int j = 0; j < 8; ++j) {
        float4 q4 = *reinterpret_cast<const float4*>(&s_v[h_l * VPAD + 4 * j]);
        rr[4*j+0]=q4.x; rr[4*j+1]=q4.y; rr[4*j+2]=q4.z; rr[4*j+3]=q4.w;
    }
    #pragma unroll
    for (int j = 0; j < 8; ++j) {
        float4 q4 = *reinterpret_cast<const float4*>(&s_v[h_l * VPAD + 32 + 4 * j]);
        ii[4*j+0]=q4.x; ii[4*j+1]=q4.y; ii[4*j+2]=q4.z; ii[4*j+3]=q4.w;
    }

    const float* wrt = w_real + ((size_t)t * MO_ + o0) * MI_;
    const float* wit = w_imag + ((size_t)t * MO_ + o0) * MI_;

    float* wsb = ws + (size_t)bt * BT_STRIDE;
    #pragma unroll
    for (int ol = 0; ol < 2; ++ol) {
        const float4* wa = reinterpret_cast<const float4*>(wrt + ol * MI_);
        const float4* wb = reinterpret_cast<const float4*>(wit + ol * MI_);
        float c = 0.f, s = 0.f;
        #pragma unroll
        for (int mq = 0; mq < 8; ++mq) {
            float4 a4 = wa[mq];
            float4 b4 = wb[mq];
            c = fmaf(rr[4*mq+0], a4.x, c); c = fmaf(-ii[4*mq+0], b4.x, c);
            s = fmaf(rr[4*mq+0], b4.x, s); s = fmaf( ii[4*mq+0], a4.x, s);
            c = fmaf(rr[4*mq+1], a4.y, c); c = fmaf(-ii[4*mq+1], b4.y, c);
            s = fmaf(rr[4*mq+1], b4.y, s); s = fmaf( ii[4*mq+1], a4.y, s);
            c = fmaf(rr[4*mq+2], a4.z, c); c = fmaf(-ii[4*mq+2], b4.z, c);
            s = fmaf(rr[4*mq+2], b4.z, s); s = fmaf( ii[4*mq+2], a4.z, s);
            c = fmaf(rr[4*mq+3], a4.w, c); c = fmaf(-ii[4*mq+3], b4.w, c);
            s = fmaf(rr[4*mq+3], b4.w, s); s = fmaf( ii[4*mq+3], a4.w, s);
        }
        const int o = o0 + ol;
        v2f p; p.x = c; p.y = s;
        *reinterpret_cast<v2f*>(&wsb[2 * (o * D_ + h_g)]) = p;
    }
}

// ---------- Kernel B v2: 2h/lane, 8-wave blocks, 2-chain rotation ----------
// grid 640; XCD-aligned: blk%8 = bt%8. block 512 = 8 waves.
// wave w: stream = qb*4 + (w>>1), half = w&1. lane owns h = half*128 + 2*lane.
// One 32KB LDS stage per block (4x/bt ws reads, as round 11).
__global__ __launch_bounds__(512, 4) void spectral_ift(
    const float* __restrict__ ws,
    float* __restrict__ out)
{
    const int b    = blockIdx.x;
    const int r    = b & 7;
    const int rest = b >> 3;           // 0..79
    const int qb   = rest & 3;
    const int q    = rest >> 2;        // 0..19
    const int bt   = 8 * q + r;
    const int wave = threadIdx.x >> 6;     // 0..7
    const int lane = threadIdx.x & 63;
    const int strm = qb * 4 + (wave >> 1); // 0..15
    const int half = wave & 1;
    const int h0   = half * 128 + lane * 2;

    __shared__ float s_cs[BT_STRIDE];  // 32 KB: [o][h] -> (C,S) pairs

    {   // cooperative stage: 32 KB, coalesced, once per block (L2-local)
        const float4* g4 = reinterpret_cast<const float4*>(
            ws + (size_t)bt * BT_STRIDE);
        float4* s4 = reinterpret_cast<float4*>(s_cs);
        #pragma unroll
        for (int i = 0; i < 4; ++i)
            s4[threadIdx.x + 512 * i] = g4[threadIdx.x + 512 * i];
    }
    __syncthreads();

    // (C,S) pairs for h0, h0+1: one ds_read_b128 per o (conflict-free)
    v2f CS0[MO_], CS1[MO_];
    #pragma unroll
    for (int o = 0; o < MO_; ++o) {
        float4 q4 = *reinterpret_cast<const float4*>(&s_cs[2 * (o * D_ + h0)]);
        CS0[o].x = q4.x; CS0[o].y = q4.y;
        CS1[o].x = q4.z; CS1[o].y = q4.w;
    }

    float* ob = out + (size_t)bt * RES_ * D_ + h0;

    #pragma unroll
    for (int k = 0; k < 7; ++k) {
        const int s = strm + 16 * k;     // wave-uniform slot
        if (s <= 100) {
            const float phi = (float)s * (TWO_PI / (float)RES_);
            float s1, c1;
            __sincosf(phi, &s1, &c1);
            // double-angle step for the two chains
            const float c2 = fmaf(c1, c1, -(s1 * s1));
            const float s2 = 2.0f * c1 * s1;

            v2f ab0 = {0.f, 0.f}, ab1 = {0.f, 0.f};
            v2f ce;  ce.x = 1.f; ce.y = 0.f;   // (cos,sin)(2j*phi)
            v2f co_; co_.x = c1; co_.y = s1;   // (cos,sin)((2j+1)*phi)
            #pragma unroll
            for (int j = 0; j < MO_ / 2; ++j) {
                ab0 = __builtin_elementwise_fma(CS0[2*j],     ce,  ab0);
                ab1 = __builtin_elementwise_fma(CS1[2*j],     ce,  ab1);
                ab0 = __builtin_elementwise_fma(CS0[2*j + 1], co_, ab0);
                ab1 = __builtin_elementwise_fma(CS1[2*j + 1], co_, ab1);
                // rotate both chains by 2*phi (independent chains, 8 steps)
                const float ne_c = fmaf(ce.x,  c2, -(ce.y  * s2));
                const float ne_s = fmaf(ce.y,  c2,  (ce.x  * s2));
                const float no_c = fmaf(co_.x, c2, -(co_.y * s2));
                const float no_s = fmaf(co_.y, c2,  (co_.x * s2));
                ce.x = ne_c; ce.y = ne_s;
                co_.x = no_c; co_.y = no_s;
            }

            const int mr = (s == 0) ? 0 : (RES_ - s);
            v2f lo, hi;
            lo.x = ab0.x - ab0.y; lo.y = ab1.x - ab1.y;
            hi.x = ab0.x + ab0.y; hi.y = ab1.x + ab1.y;
            // 64 lanes x 8B = 512B contiguous run per store
            __builtin_nontemporal_store(
                lo, reinterpret_cast<v2f*>(&ob[(size_t)s  * D_]));
            __builtin_nontemporal_store(
                hi, reinterpret_cast<v2f*>(&ob[(size_t)mr * D_]));
        }
    }
}

extern "C" void kernel_launch(void* const* d_in, const int* in_sizes, int n_in,
                              void* d_out, int out_size, void* d_ws, size_t ws_size,
                              hipStream_t stream) {
    const float* v  = (const float*)d_in[0];
    const float* wr = (const float*)d_in[1];
    const float* wi = (const float*)d_in[2];
    float* out = (float*)d_out;
    float* ws  = (float*)d_ws;

    spectral_cs <<<B_ * T_ * NHS, 256, 0, stream>>>(v, wr, wi, ws);
    spectral_ift<<<B_ * T_ * 4,   512, 0, stream>>>(ws, out);
}

// Round 15
// 21.581 us; speedup vs baseline: 1.9850x; 1.0307x over previous
//
#include <hip/hip_runtime.h>

#define B_   16
#define T_   10
#define D_   256
#define MI_  32
#define MO_  16
#define RES_ 200
#define TWO_PI 6.28318530717958647692f

#define HSLICE 32
#define NHS    (D_ / HSLICE)              // 8
#define VPAD   68
#define BT_STRIDE (2 * MO_ * D_)          // 8192 floats: [o][h] -> (C,S) pairs

using f32x4 = __attribute__((ext_vector_type(4))) float;
using v2f   = __attribute__((ext_vector_type(2))) float;

// ---------- Kernel A: contraction -> ws[bt][o][h] = (C,S) interleaved ------
// grid 1280; XCD-aligned: blk%8 = bt%8. ROUND-11 EXACT (~7.3us incl launch).
__global__ __launch_bounds__(256) void spectral_cs(
    const float* __restrict__ v,
    const float* __restrict__ w_real,
    const float* __restrict__ w_imag,
    float* __restrict__ ws)
{
    const int a    = blockIdx.x;
    const int r    = a & 7;
    const int rest = a >> 3;           // 0..159
    const int hs   = rest & 7;
    const int q    = rest >> 3;        // 0..19
    const int bt   = 8 * q + r;
    const int t    = bt % T_;

    __shared__ float s_v[HSLICE * VPAD];     // 8.5 KB

    {   // cooperative v-slice stage (v read exactly once per element)
        const float4* gv = reinterpret_cast<const float4*>(
            v + ((size_t)bt * D_ + hs * HSLICE) * (2 * MI_));
        #pragma unroll
        for (int j = 0; j < 2; ++j) {
            const int f = threadIdx.x + 256 * j;
            const int h = f >> 4;
            const int m = (f & 15) * 4;
            *reinterpret_cast<float4*>(&s_v[h * VPAD + m]) = gv[f];
        }
    }
    __syncthreads();

    const int og  = threadIdx.x >> 5;
    const int h_l = threadIdx.x & 31;
    const int o0  = og * 2;
    const int h_g = hs * HSLICE + h_l;

    float rr[MI_], ii[MI_];
    #pragma unroll
    for (int j = 0; j < 8; ++j) {
        float4 q4 = *reinterpret_cast<const float4*>(&s_v[h_l * VPAD + 4 * j]);
        rr[4*j+0]=q4.x; rr[4*j+1]=q4.y; rr[4*j+2]=q4.z; rr[4*j+3]=q4.w;
    }
    #pragma unroll
    for (int j = 0; j < 8; ++j) {
        float4 q4 = *reinterpret_cast<const float4*>(&s_v[h_l * VPAD + 32 + 4 * j]);
        ii[4*j+0]=q4.x; ii[4*j+1]=q4.y; ii[4*j+2]=q4.z; ii[4*j+3]=q4.w;
    }

    const float* wrt = w_real + ((size_t)t * MO_ + o0) * MI_;
    const float* wit = w_imag + ((size_t)t * MO_ + o0) * MI_;

    float* wsb = ws + (size_t)bt * BT_STRIDE;
    #pragma unroll
    for (int ol = 0; ol < 2; ++ol) {
        const float4* wa = reinterpret_cast<const float4*>(wrt + ol * MI_);
        const float4* wb = reinterpret_cast<const float4*>(wit + ol * MI_);
        float c = 0.f, s = 0.f;
        #pragma unroll
        for (int mq = 0; mq < 8; ++mq) {
            float4 a4 = wa[mq];
            float4 b4 = wb[mq];
            c = fmaf(rr[4*mq+0], a4.x, c); c = fmaf(-ii[4*mq+0], b4.x, c);
            s = fmaf(rr[4*mq+0], b4.x, s); s = fmaf( ii[4*mq+0], a4.x, s);
            c = fmaf(rr[4*mq+1], a4.y, c); c = fmaf(-ii[4*mq+1], b4.y, c);
            s = fmaf(rr[4*mq+1], b4.y, s); s = fmaf( ii[4*mq+1], a4.y, s);
            c = fmaf(rr[4*mq+2], a4.z, c); c = fmaf(-ii[4*mq+2], b4.z, c);
            s = fmaf(rr[4*mq+2], b4.z, s); s = fmaf( ii[4*mq+2], a4.z, s);
            c = fmaf(rr[4*mq+3], a4.w, c); c = fmaf(-ii[4*mq+3], b4.w, c);
            s = fmaf(rr[4*mq+3], b4.w, s); s = fmaf( ii[4*mq+3], a4.w, s);
        }
        const int o = o0 + ol;
        v2f p; p.x = c; p.y = s;
        // interleaved pair store: 32 lanes x 8B = 256B contiguous run
        *reinterpret_cast<v2f*>(&wsb[2 * (o * D_ + h_g)]) = p;
    }
}

// ---------- Kernel B v3: NO LDS, direct global CS, hoisted sincos ----------
// grid 640; XCD-aligned: blk%8 = bt%8. block 256 = 4 independent waves
// (no __syncthreads). wave = full output row; lane owns h = 4*lane..4*lane+3.
// CS regs fill via 16 global b128 loads (L2-local); 7 slot sincos computed
// under the load shadow; rotation-recurrence per slot; 1KB NT wave stores.
__global__ __launch_bounds__(256) void spectral_ift(
    const float* __restrict__ ws,
    float* __restrict__ out)
{
    const int b    = blockIdx.x;
    const int r    = b & 7;
    const int rest = b >> 3;           // 0..79
    const int qb   = rest & 3;
    const int q    = rest >> 2;        // 0..19
    const int bt   = 8 * q + r;
    const int wave = threadIdx.x >> 6;
    const int lane = threadIdx.x & 63;
    const int g    = qb * 4 + wave;    // 0..15
    const int h0   = lane * 4;

    // per-lane C,S registers straight from global (16 overlapped b128 loads)
    const float* wsb = ws + (size_t)bt * BT_STRIDE;
    v2f CS0[MO_], CS1[MO_], CS2[MO_], CS3[MO_];
    #pragma unroll
    for (int o = 0; o < MO_; ++o) {
        float4 q0 = *reinterpret_cast<const float4*>(&wsb[2 * (o * D_ + h0)]);
        float4 q1 = *reinterpret_cast<const float4*>(&wsb[2 * (o * D_ + h0) + 4]);
        CS0[o].x = q0.x; CS0[o].y = q0.y;
        CS1[o].x = q0.z; CS1[o].y = q0.w;
        CS2[o].x = q1.x; CS2[o].y = q1.y;
        CS3[o].x = q1.z; CS3[o].y = q1.w;
    }

    // hoisted slot trig (independent of the loads -> fills the load shadow)
    float cph[7], sph[7];
    #pragma unroll
    for (int k = 0; k < 7; ++k) {
        const int s = g + 16 * k;
        const float phi = (float)s * (TWO_PI / (float)RES_);
        __sincosf(phi, &sph[k], &cph[k]);
    }

    float* ob = out + (size_t)bt * RES_ * D_;

    #pragma unroll
    for (int k = 0; k < 7; ++k) {
        const int s = g + 16 * k;        // wave-uniform slot
        if (s <= 100) {
            const float c1 = cph[k];
            const float s1 = sph[k];

            v2f ab0 = {0.f, 0.f}, ab1 = {0.f, 0.f};
            v2f ab2 = {0.f, 0.f}, ab3 = {0.f, 0.f};
            v2f cs;  cs.x = 1.f; cs.y = 0.f;      // (cos(o*phi), sin(o*phi))
            #pragma unroll
            for (int o = 0; o < MO_; ++o) {
                ab0 = __builtin_elementwise_fma(CS0[o], cs, ab0);
                ab1 = __builtin_elementwise_fma(CS1[o], cs, ab1);
                ab2 = __builtin_elementwise_fma(CS2[o], cs, ab2);
                ab3 = __builtin_elementwise_fma(CS3[o], cs, ab3);
                const float nc = fmaf(cs.x, c1, -(cs.y * s1));
                const float ns = fmaf(cs.y, c1,  (cs.x * s1));
                cs.x = nc; cs.y = ns;
            }

            const int mr = (s == 0) ? 0 : (RES_ - s);
            f32x4 lo, hi;
            lo.x = ab0.x - ab0.y; hi.x = ab0.x + ab0.y;
            lo.y = ab1.x - ab1.y; hi.y = ab1.x + ab1.y;
            lo.z = ab2.x - ab2.y; hi.z = ab2.x + ab2.y;
            lo.w = ab3.x - ab3.y; hi.w = ab3.x + ab3.y;
            // full-row wave store: 64 lanes x 16B = 1KB contiguous
            __builtin_nontemporal_store(
                lo, reinterpret_cast<f32x4*>(&ob[(size_t)s  * D_ + h0]));
            __builtin_nontemporal_store(
                hi, reinterpret_cast<f32x4*>(&ob[(size_t)mr * D_ + h0]));
        }
    }
}

extern "C" void kernel_launch(void* const* d_in, const int* in_sizes, int n_in,
                              void* d_out, int out_size, void* d_ws, size_t ws_size,
                              hipStream_t stream) {
    const float* v  = (const float*)d_in[0];
    const float* wr = (const float*)d_in[1];
    const float* wi = (const float*)d_in[2];
    float* out = (float*)d_out;
    float* ws  = (float*)d_ws;

    spectral_cs <<<B_ * T_ * NHS, 256, 0, stream>>>(v, wr, wi, ws);
    spectral_ift<<<B_ * T_ * 4,   256, 0, stream>>>(ws, out);
}